// Round 20
// baseline (299.028 us; speedup 1.0000x reference)
//
#include <hip/hip_runtime.h>

// Problem constants
#define BTOT 16384
#define NI   16
#define HD   256
#define BB   2            // elements per block; waves partition OUTPUT COLS (strips)
#define NMID 3
#define ASH  264          // h LDS row stride in bf16 (528B)
#define SLS  20           // slater scratch row stride (floats)
#define HALF_LOGFACT 15.3359295387f  // 0.5 * ln(16!)

typedef short  bf16x8 __attribute__((ext_vector_type(8)));
typedef float  f32x4  __attribute__((ext_vector_type(4)));

__device__ __forceinline__ unsigned short f2bf(float f) {   // prep kernel only
    unsigned u = __builtin_bit_cast(unsigned, f);
    u += 0x7FFFu + ((u >> 16) & 1u);
    return (unsigned short)(u >> 16);
}
__device__ __forceinline__ unsigned cvt_pk_bf16(float lo, float hi) {
    unsigned d;
    asm("v_cvt_pk_bf16_f32 %0, %1, %2" : "=v"(d) : "v"(lo), "v"(hi));
    return d;
}
__device__ __forceinline__ float bflo(unsigned u) { return __builtin_bit_cast(float, u << 16); }
__device__ __forceinline__ float bfhi(unsigned u) { return __builtin_bit_cast(float, u & 0xFFFF0000u); }
__device__ __forceinline__ float bcast(float x, int lane) {
    return __builtin_bit_cast(float,
        __builtin_amdgcn_readlane(__builtin_bit_cast(int, x), lane));
}
// tanh(x) = 1 - 2/(1 + 2^(x*2*log2(e))) : 5 VALU ops
__device__ __forceinline__ float tanh5(float x) {
    float z = __builtin_amdgcn_exp2f(x * 2.885390081777927f);
    return __builtin_fmaf(-2.0f, __builtin_amdgcn_rcpf(1.0f + z), 1.0f);
}
#define LGKM_BAR() do { asm volatile("s_waitcnt lgkmcnt(0)" ::: "memory"); \
    __builtin_amdgcn_s_barrier(); __builtin_amdgcn_sched_barrier(0); } while (0)
#define LGKM_WAIT() do { asm volatile("s_waitcnt lgkmcnt(0)" ::: "memory"); \
    __builtin_amdgcn_sched_barrier(0); } while (0)

// ---- prep: chunked fragment-order weights (verified R6-R19).
// Chunk fc<48: (layer=fc>>4, ch=fc&15): dst[kg*128 + j*8 + kk] = Wmid[layer][8kg+kk][ch*16+j],
//   kg in [0,64). Chunk 48: Wsl, kg in [0,32), rest zero.
__global__ void prep_w(const float* __restrict__ Wmid, const float* __restrict__ Wsl,
                       unsigned short* __restrict__ wtc) {
    const int b = blockIdx.x;       // 0..48
    const int t = threadIdx.x;
    unsigned short* dst = wtc + (size_t)b * 8192;
    if (b < 48) {
        const int layer = b >> 4, ch = b & 15;
        const float* src = Wmid + (size_t)layer * (2 * HD * HD);
#pragma unroll 4
        for (int v = 0; v < 32; ++v) {
            int o = t * 32 + v;
            int kk = o & 7, j = (o >> 3) & 15, kg = o >> 7;
            dst[o] = f2bf(src[(8 * kg + kk) * HD + ch * 16 + j]);
        }
    } else {
#pragma unroll 4
        for (int v = 0; v < 32; ++v) {
            int o = t * 32 + v;
            int kk = o & 7, j = (o >> 3) & 15, kg = o >> 7;
            dst[o] = (kg < 32) ? f2bf(Wsl[(8 * kg + kk) * NI + j]) : (unsigned short)0;
        }
    }
}

struct __align__(16) SMem {
    union {
        unsigned short h[BB * NI * ASH];  // 16896 B: bf16 h, shared across strips
        float slf[BB][NI * ASH / 2];      // slater scratch overlays element e's h
    } u;
    unsigned short gmgv[BB * HD];         // 1024 B: gm at layer top; gv overwrites
                                          // (wave-private strip cols) after barrier C
};
static_assert(sizeof(SMem) == 17920, "4 blocks/CU needs <= ~40KB");

__global__ __launch_bounds__(256, 4)
void eqslater_mfma(const float* __restrict__ x0g,
                   const float* __restrict__ Win,
                   const float* __restrict__ bin,
                   const float* __restrict__ bmid,
                   const float* __restrict__ bsl,
                   const float* __restrict__ width,
                   const unsigned short* __restrict__ wtc,
                   float* __restrict__ out) {
    __shared__ SMem sm;
    const int tid = threadIdx.x;
    const int bbase = blockIdx.x * BB;
    const int w = tid >> 6;   // wave = output-column STRIP [64w, 64w+64)
    const int l = tid & 63;
    const int c = l & 15;     // A-row (chunk-local j) / B-col (h-row) / C-col
    const int g = l >> 4;     // k-group; C rows 4g..4g+3 -> cols j = 16ch+4g+q
    const int j4 = 4 * g;
    const int B0 = 64 * w;    // strip base column

    const unsigned short* wlane = wtc + (size_t)g * 128 + (size_t)c * 8;

    // ---- x0 + per-element means (lane l holds x0[el=(l>>4)&1][r=l&15], dup x2)
    float x0v = x0g[bbase * NI + (l & 31)];
    {
        float ssum = x0v;
#pragma unroll
        for (int off = 8; off > 0; off >>= 1) ssum += __shfl_xor(ssum, off);
        // lanes of each 16-group hold gmean of their el
        const int jc = B0 + l;
        const float w0 = Win[jc], w1 = Win[HD + jc], bj = bin[jc];
#pragma unroll
        for (int el = 0; el < BB; ++el) {
            float ge = bcast(ssum, el * 16) * 0.0625f;
            float gl = __builtin_fmaf(ge, w1, bj);
#pragma unroll 4
            for (int r = 0; r < NI; ++r) {
                float xv = bcast(x0v, el * 16 + r);
                float f = tanh5(__builtin_fmaf(xv, w0, gl));
                sm.u.h[(el * NI + r) * ASH + jc] =
                    (unsigned short)cvt_pk_bf16(f, f);
            }
        }
    }
    LGKM_BAR();   // h complete (all strips)

    bf16x8 afE[BB][8], sbufG[8];

#pragma unroll 1
    for (int layer = 0; layer < NMID; ++layer) {
        // ---- gm pass: lane (el2 = l>>5) sums 2 cols (uint) of its strip
        {
            const int el2 = l >> 5;
            const int c0 = B0 + (l & 31) * 2;
            float s0 = 0, s1 = 0;
#pragma unroll
            for (int r = 0; r < NI; ++r) {
                unsigned d = *(const unsigned*)&sm.u.h[(el2 * NI + r) * ASH + c0];
                s0 += bflo(d); s1 += bfhi(d);
            }
            *(unsigned*)&sm.gmgv[el2 * HD + c0] = cvt_pk_bf16(s0 * 0.0625f, s1 * 0.0625f);
        }
        LGKM_BAR();   // (B) gm writes complete

        // replicated-gm B frags (B col r = gm of element r&1) -> registers
#pragma unroll
        for (int s = 0; s < 8; ++s)
            sbufG[s] = *(const bf16x8*)&sm.gmgv[(c & 1) * HD + 32 * s + 8 * g];
        LGKM_BAR();   // (C) ALL waves' gm reads retired -> gmgv reusable as gv

        const float* bml = bmid + layer * HD;

        // ---- per-layer gm-GEMM phase (afE NOT live here -> low pressure)
#pragma unroll 1
        for (int cc = 0; cc < 4; ++cc) {
            const int ch = 4 * w + cc;
            const unsigned short* cb2 = wlane + (size_t)(layer * 16 + ch) * 8192 + 4096;
            f32x4 aG0 = {0.f,0.f,0.f,0.f}, aG1 = {0.f,0.f,0.f,0.f};
#pragma unroll
            for (int half = 0; half < 2; ++half) {
                bf16x8 wfh[4];
#pragma unroll
                for (int s = 0; s < 4; ++s)
                    wfh[s] = *(const bf16x8*)(cb2 + (4 * half + s) * 512);
                aG0 = __builtin_amdgcn_mfma_f32_16x16x32_bf16(wfh[0], sbufG[4 * half],     aG0, 0, 0, 0);
                aG1 = __builtin_amdgcn_mfma_f32_16x16x32_bf16(wfh[1], sbufG[4 * half + 1], aG1, 0, 0, 0);
                aG0 = __builtin_amdgcn_mfma_f32_16x16x32_bf16(wfh[2], sbufG[4 * half + 2], aG0, 0, 0, 0);
                aG1 = __builtin_amdgcn_mfma_f32_16x16x32_bf16(wfh[3], sbufG[4 * half + 3], aG1, 0, 0, 0);
            }
            f32x4 accG = aG0 + aG1;
            const float4 bv = *(const float4*)&bml[ch * 16 + j4];
            // lane (g,c): gvec[el=c&1][j=16ch+4g+q]; lanes c>=2 duplicate
            if (c < BB) {
                uint2 go;
                go.x = cvt_pk_bf16(accG[0] + bv.x, accG[1] + bv.y);
                go.y = cvt_pk_bf16(accG[2] + bv.z, accG[3] + bv.w);
                *(uint2*)&sm.gmgv[c * HD + ch * 16 + j4] = go;
            }
        }

        // ---- register B-frags for both elements (pre-layer h)
#pragma unroll
        for (int el = 0; el < BB; ++el)
#pragma unroll
            for (int s = 0; s < 8; ++s)
                afE[el][s] = *(const bf16x8*)&sm.u.h[(el * NI + c) * ASH + 32 * s + 8 * g];
        LGKM_BAR();   // (D) afE snapshots done before ANY strip's epilogue writes

        // ---- h-part chunk loop (no stash: both els register-resident)
#pragma unroll 1
        for (int cc = 0; cc < 4; ++cc) {
            const int ch = 4 * w + cc;
            const unsigned short* cb = wlane + (size_t)(layer * 16 + ch) * 8192;
            f32x4 acc0 = {0.f,0.f,0.f,0.f}, acc1 = {0.f,0.f,0.f,0.f};
#pragma unroll
            for (int half = 0; half < 2; ++half) {
                bf16x8 wfh[4];
#pragma unroll
                for (int s = 0; s < 4; ++s)
                    wfh[s] = *(const bf16x8*)(cb + (4 * half + s) * 512);
#pragma unroll
                for (int s = 0; s < 4; ++s) {
                    acc0 = __builtin_amdgcn_mfma_f32_16x16x32_bf16(wfh[s], afE[0][4 * half + s], acc0, 0, 0, 0);
                    acc1 = __builtin_amdgcn_mfma_f32_16x16x32_bf16(wfh[s], afE[1][4 * half + s], acc1, 0, 0, 0);
                }
            }
            // ---- epilogues (2 els): h[el][c][j] = tanh(acc + gv) + h_old
#pragma unroll
            for (int el = 0; el < BB; ++el) {
                f32x4 acc = (el == 0) ? acc0 : acc1;
                const uint2 gd = *(const uint2*)&sm.gmgv[el * HD + ch * 16 + j4];
                unsigned short* hrow = &sm.u.h[(el * NI + c) * ASH + ch * 16 + j4];
                uint2 hd2 = *(const uint2*)hrow;
                float f0 = tanh5(acc[0] + bflo(gd.x)) + bflo(hd2.x);
                float f1 = tanh5(acc[1] + bfhi(gd.x)) + bfhi(hd2.x);
                float f2 = tanh5(acc[2] + bflo(gd.y)) + bflo(hd2.y);
                float f3 = tanh5(acc[3] + bfhi(gd.y)) + bfhi(hd2.y);
                uint2 wo; wo.x = cvt_pk_bf16(f0, f1); wo.y = cvt_pk_bf16(f2, f3);
                *(uint2*)hrow = wo;
            }
        }
        LGKM_BAR();   // (A) all strips' epilogue writes done
    }

    // ---- slater head + LU: waves 0,1 own elements 0,1 (waves 2,3 retire)
    if (w < BB) {
        const int e = w;
        {
            bf16x8 sb8[8];
#pragma unroll
            for (int s = 0; s < 8; ++s)
                sb8[s] = *(const bf16x8*)&sm.u.h[(e * NI + c) * ASH + 32 * s + 8 * g];
            const unsigned short* cb = wlane + (size_t)48 * 8192;
            f32x4 a0 = {0.f,0.f,0.f,0.f}, a1 = {0.f,0.f,0.f,0.f};
#pragma unroll
            for (int s = 0; s < 4; ++s) {
                bf16x8 b0 = *(const bf16x8*)(cb + (2 * s) * 512);
                bf16x8 b1 = *(const bf16x8*)(cb + (2 * s + 1) * 512);
                a0 = __builtin_amdgcn_mfma_f32_16x16x32_bf16(b0, sb8[2 * s],     a0, 0, 0, 0);
                a1 = __builtin_amdgcn_mfma_f32_16x16x32_bf16(b1, sb8[2 * s + 1], a1, 0, 0, 0);
            }
            f32x4 sv = a0 + a1;   // lane (g,c): sl[row r=c][m=4g+q]
            const float4 bsv = *(const float4*)&bsl[j4];
            float* slp = &sm.u.slf[e][0];   // overlays own element's h (now dead)
            float4 o;
            o.x = sv[0] + bsv.x; o.y = sv[1] + bsv.y;
            o.z = sv[2] + bsv.z; o.w = sv[3] + bsv.w;
            *(float4*)&slp[c * SLS + j4] = o;
        }
        LGKM_WAIT();   // in-wave: slf visible

        // ---- per-wave slogdet: swap-free LU w/ partial pivoting (R11-R19)
        const float* slp = &sm.u.slf[e][0];
        const int i = c;
        float M[16];
#pragma unroll
        for (int jj = 0; jj < 4; ++jj) {
            float4 vv = *(const float4*)&slp[i * SLS + 4 * jj];
            M[4 * jj] = vv.x; M[4 * jj + 1] = vv.y; M[4 * jj + 2] = vv.z; M[4 * jj + 3] = vv.w;
        }

        int elim = 0;
        unsigned chosen = 0;
        int invcnt = 0;
        float dsign = 1.f, logabs = 0.f;
#pragma unroll
        for (int k = 0; k < 16; ++k) {
            float myv = elim ? -1.f : __builtin_fabsf(M[k]);
            float maxv = myv;
#pragma unroll
            for (int off = 8; off > 0; off >>= 1)
                maxv = fmaxf(maxv, __shfl_xor(maxv, off));
            unsigned long long bal = __ballot(myv == maxv);
            const int p = (__ffsll((long long)bal) - 1) & 15;

            invcnt += __popc(chosen >> (p + 1));
            chosen |= 1u << p;
            if (i == p) elim = 1;

            float piv = bcast(M[k], p);
            float ap = fmaxf(__builtin_fabsf(piv), 1e-35f);
            logabs += __logf(ap);
            if (piv < 0.f) dsign = -dsign;
            float spiv = __builtin_copysignf(ap, piv);
            float mi = __fdividef(M[k], spiv);
#pragma unroll
            for (int j = k + 1; j < 16; ++j) {
                float pr = bcast(M[j], p);
                if (!elim) M[j] = __builtin_fmaf(-mi, pr, M[j]);
            }
        }
        if (invcnt & 1) dsign = -dsign;

        float xv = (l < NI) ? x0g[(bbase + e) * NI + l] : 0.f;
        float sq = xv * xv;
#pragma unroll
        for (int off = 8; off > 0; off >>= 1) sq += __shfl_xor(sq, off);

        if (l == 0) {
            out[bbase + e] = dsign;
            out[BTOT + bbase + e] = logabs - HALF_LOGFACT - width[0] * sq;
        }
    }
}

extern "C" void kernel_launch(void* const* d_in, const int* in_sizes, int n_in,
                              void* d_out, int out_size, void* d_ws, size_t ws_size,
                              hipStream_t stream) {
    const float* x0   = (const float*)d_in[0];
    const float* Win  = (const float*)d_in[1];
    const float* bin  = (const float*)d_in[2];
    const float* Wmid = (const float*)d_in[3];
    const float* bmid = (const float*)d_in[4];
    const float* Wsl  = (const float*)d_in[5];
    const float* bsl  = (const float*)d_in[6];
    const float* wid  = (const float*)d_in[7];
    float* out = (float*)d_out;

    unsigned short* wtc = (unsigned short*)d_ws;   // 49 * 16384 B = 802816 B

    hipLaunchKernelGGL(prep_w, dim3(49), dim3(256), 0, stream, Wmid, Wsl, wtc);
    hipLaunchKernelGGL(eqslater_mfma, dim3(BTOT / BB), dim3(256), 0, stream,
                       x0, Win, bin, bmid, bsl, wid, wtc, out);
}

// Round 21
// 246.863 us; speedup vs baseline: 1.2113x; 1.2113x over previous
//
#include <hip/hip_runtime.h>

// Problem constants
#define BTOT 16384
#define NI   16
#define HD   256
#define BB   4            // elements per block; waves partition OUTPUT COLS (strips)
#define NMID 3
#define ASH  264          // h/stash LDS row stride in bf16 (528B)
#define SLS  20           // slater scratch row stride (floats)
#define HALF_LOGFACT 15.3359295387f  // 0.5 * ln(16!)

typedef short  bf16x8 __attribute__((ext_vector_type(8)));
typedef float  f32x4  __attribute__((ext_vector_type(4)));

__device__ __forceinline__ unsigned short f2bf(float f) {   // prep kernel only
    unsigned u = __builtin_bit_cast(unsigned, f);
    u += 0x7FFFu + ((u >> 16) & 1u);
    return (unsigned short)(u >> 16);
}
__device__ __forceinline__ unsigned cvt_pk_bf16(float lo, float hi) {
    unsigned d;
    asm("v_cvt_pk_bf16_f32 %0, %1, %2" : "=v"(d) : "v"(lo), "v"(hi));
    return d;
}
__device__ __forceinline__ float bflo(unsigned u) { return __builtin_bit_cast(float, u << 16); }
__device__ __forceinline__ float bfhi(unsigned u) { return __builtin_bit_cast(float, u & 0xFFFF0000u); }
__device__ __forceinline__ float bcast(float x, int lane) {
    return __builtin_bit_cast(float,
        __builtin_amdgcn_readlane(__builtin_bit_cast(int, x), lane));
}
// tanh(x) = 1 - 2/(1 + 2^(x*2*log2(e))) : 5 VALU ops
__device__ __forceinline__ float tanh5(float x) {
    float z = __builtin_amdgcn_exp2f(x * 2.885390081777927f);
    return __builtin_fmaf(-2.0f, __builtin_amdgcn_rcpf(1.0f + z), 1.0f);
}
#define LGKM_BAR() do { asm volatile("s_waitcnt lgkmcnt(0)" ::: "memory"); \
    __builtin_amdgcn_s_barrier(); __builtin_amdgcn_sched_barrier(0); } while (0)
#define LGKM_WAIT() do { asm volatile("s_waitcnt lgkmcnt(0)" ::: "memory"); \
    __builtin_amdgcn_sched_barrier(0); } while (0)

// ---- prep: chunked fragment-order weights (verified R6-R20).
// Chunk fc<48: (layer=fc>>4, ch=fc&15): dst[kg*128 + j*8 + kk] = Wmid[layer][8kg+kk][ch*16+j],
//   kg in [0,64). Chunk 48: Wsl, kg in [0,32), rest zero.
__global__ void prep_w(const float* __restrict__ Wmid, const float* __restrict__ Wsl,
                       unsigned short* __restrict__ wtc) {
    const int b = blockIdx.x;       // 0..48
    const int t = threadIdx.x;
    unsigned short* dst = wtc + (size_t)b * 8192;
    if (b < 48) {
        const int layer = b >> 4, ch = b & 15;
        const float* src = Wmid + (size_t)layer * (2 * HD * HD);
#pragma unroll 4
        for (int v = 0; v < 32; ++v) {
            int o = t * 32 + v;
            int kk = o & 7, j = (o >> 3) & 15, kg = o >> 7;
            dst[o] = f2bf(src[(8 * kg + kk) * HD + ch * 16 + j]);
        }
    } else {
#pragma unroll 4
        for (int v = 0; v < 32; ++v) {
            int o = t * 32 + v;
            int kk = o & 7, j = (o >> 3) & 15, kg = o >> 7;
            dst[o] = (kg < 32) ? f2bf(Wsl[(8 * kg + kk) * NI + j]) : (unsigned short)0;
        }
    }
}

struct __align__(16) SMem {
    union {
        unsigned short h[BB * NI * ASH];  // 33792 B: bf16 h, shared across strips
        float slf[BB][NI * ASH / 2];      // slater scratch overlays element e's h
    } u;
    unsigned short stash[2 * NI * ASH];   // 16896 B: pre-layer h snapshot of el 2,3
    unsigned short gmgv[BB * HD];         // 2048 B: gm at layer top; gv overwrites
                                          // (wave-private strip cols) after barrier C
};
static_assert(sizeof(SMem) == 52736, "R6-proven 3-blocks/CU size");

__global__ __launch_bounds__(256, 3)
void eqslater_mfma(const float* __restrict__ x0g,
                   const float* __restrict__ Win,
                   const float* __restrict__ bin,
                   const float* __restrict__ bmid,
                   const float* __restrict__ bsl,
                   const float* __restrict__ width,
                   const unsigned short* __restrict__ wtc,
                   float* __restrict__ out) {
    __shared__ SMem sm;
    const int tid = threadIdx.x;
    const int bbase = blockIdx.x * BB;
    const int w = tid >> 6;   // wave = output-column STRIP [64w, 64w+64)
    const int l = tid & 63;
    const int c = l & 15;     // A-row (chunk-local j) / B-col (h-row) / C-col
    const int g = l >> 4;     // k-group; C rows 4g..4g+3 -> cols j = 16ch+4g+q
    const int j4 = 4 * g;
    const int B0 = 64 * w;    // strip base column

    const unsigned short* wlane = wtc + (size_t)g * 128 + (size_t)c * 8;

    // ---- x0 + per-element means (lane l holds x0[el=l>>4][r=l&15])
    float x0v = x0g[bbase * NI + l];
    {
        float ssum = x0v;
#pragma unroll
        for (int off = 8; off > 0; off >>= 1) ssum += __shfl_xor(ssum, off);
        const float gme = ssum * 0.0625f;
        const int jc = B0 + l;
        const float w0 = Win[jc], w1 = Win[HD + jc], bj = bin[jc];
#pragma unroll
        for (int el = 0; el < 4; ++el) {
            float ge = bcast(gme, el * 16);
            float gl = __builtin_fmaf(ge, w1, bj);
#pragma unroll 4
            for (int r = 0; r < NI; ++r) {
                float xv = bcast(x0v, el * 16 + r);
                float f = tanh5(__builtin_fmaf(xv, w0, gl));
                sm.u.h[(el * NI + r) * ASH + jc] =
                    (unsigned short)cvt_pk_bf16(f, f);
            }
        }
    }
    LGKM_BAR();   // h complete (all strips)

    bf16x8 afE[2][8], sbufG[8];

#pragma unroll 1
    for (int layer = 0; layer < NMID; ++layer) {
        // ---- stash pre-layer h of elements 2,3 (cooperative copy, 64B/thread)
        {
            const int r32 = tid >> 3;          // 0..31 -> el2 rows, el3 rows
            const int seg = tid & 7;           // 32-col segment
            const unsigned short* srcp = &sm.u.h[(32 + r32) * ASH + seg * 32];
            unsigned short* dstp = &sm.stash[r32 * ASH + seg * 32];
#pragma unroll
            for (int p = 0; p < 4; ++p)
                *(uint4*)(dstp + p * 8) = *(const uint4*)(srcp + p * 8);
        }
        // ---- gm pass: lane (el2 = l>>4) sums 4 cols (uint2) of its strip
        {
            const int el2 = l >> 4;
            const int c0 = B0 + (l & 15) * 4;
            float s0 = 0, s1 = 0, s2 = 0, s3 = 0;
#pragma unroll
            for (int r = 0; r < NI; ++r) {
                uint2 d = *(const uint2*)&sm.u.h[(el2 * NI + r) * ASH + c0];
                s0 += bflo(d.x); s1 += bfhi(d.x);
                s2 += bflo(d.y); s3 += bfhi(d.y);
            }
            uint2 go;
            go.x = cvt_pk_bf16(s0 * 0.0625f, s1 * 0.0625f);
            go.y = cvt_pk_bf16(s2 * 0.0625f, s3 * 0.0625f);
            *(uint2*)&sm.gmgv[el2 * HD + c0] = go;
        }
        LGKM_BAR();   // (B) gm + stash writes complete

        // replicated-gm B frags (B col r = gm of element r&3) -> registers
#pragma unroll
        for (int s = 0; s < 8; ++s)
            sbufG[s] = *(const bf16x8*)&sm.gmgv[(c & 3) * HD + 32 * s + 8 * g];
        LGKM_BAR();   // (C) ALL waves' gm reads retired -> gmgv reusable as gv

        const float* bml = bmid + layer * HD;

        // ---- per-layer gm-GEMM phase (afE NOT live here -> low pressure)
#pragma unroll 1
        for (int cc = 0; cc < 4; ++cc) {
            const int ch = 4 * w + cc;
            const unsigned short* cb2 = wlane + (size_t)(layer * 16 + ch) * 8192 + 4096;
            f32x4 aG0 = {0.f,0.f,0.f,0.f}, aG1 = {0.f,0.f,0.f,0.f};
#pragma unroll
            for (int half = 0; half < 2; ++half) {
                bf16x8 wfh[4];
#pragma unroll
                for (int s = 0; s < 4; ++s)
                    wfh[s] = *(const bf16x8*)(cb2 + (4 * half + s) * 512);
                __builtin_amdgcn_s_setprio(1);
                aG0 = __builtin_amdgcn_mfma_f32_16x16x32_bf16(wfh[0], sbufG[4 * half],     aG0, 0, 0, 0);
                aG1 = __builtin_amdgcn_mfma_f32_16x16x32_bf16(wfh[1], sbufG[4 * half + 1], aG1, 0, 0, 0);
                aG0 = __builtin_amdgcn_mfma_f32_16x16x32_bf16(wfh[2], sbufG[4 * half + 2], aG0, 0, 0, 0);
                aG1 = __builtin_amdgcn_mfma_f32_16x16x32_bf16(wfh[3], sbufG[4 * half + 3], aG1, 0, 0, 0);
                __builtin_amdgcn_s_setprio(0);
            }
            f32x4 accG = aG0 + aG1;
            const float4 bv = *(const float4*)&bml[ch * 16 + j4];
            // lane (g,c): gvec[el=c&3][j=16ch+4g+q]; lanes c>=4 duplicate
            if (c < 4) {
                uint2 go;
                go.x = cvt_pk_bf16(accG[0] + bv.x, accG[1] + bv.y);
                go.y = cvt_pk_bf16(accG[2] + bv.z, accG[3] + bv.w);
                *(uint2*)&sm.gmgv[c * HD + ch * 16 + j4] = go;
            }
        }

        // ---- register B-frags for elements 0,1 (pre-layer h)
#pragma unroll
        for (int el = 0; el < 2; ++el)
#pragma unroll
            for (int s = 0; s < 8; ++s)
                afE[el][s] = *(const bf16x8*)&sm.u.h[(el * NI + c) * ASH + 32 * s + 8 * g];
        LGKM_BAR();   // (D) afE snapshots done before ANY strip's epilogue writes

        // ---- h-part chunk loop: W-load pipeline (unconditional prefetch;
        //      chunk fc+1 always in-bounds: fc<=47 -> fc+1<=48=slater chunk)
        bf16x8 wfA[4];
        {
            const unsigned short* cb0 = wlane + (size_t)(layer * 16 + 4 * w) * 8192;
#pragma unroll
            for (int s = 0; s < 4; ++s)
                wfA[s] = *(const bf16x8*)(cb0 + s * 512);
        }
#pragma unroll 1
        for (int cc = 0; cc < 4; ++cc) {
            const int ch = 4 * w + cc;
            const unsigned short* cb = wlane + (size_t)(layer * 16 + ch) * 8192;
            bf16x8 wfB[4], sb[4];
#pragma unroll
            for (int s = 0; s < 4; ++s)
                wfB[s] = *(const bf16x8*)(cb + (4 + s) * 512);

            f32x4 acc0 = {0.f,0.f,0.f,0.f}, acc1 = {0.f,0.f,0.f,0.f};
            f32x4 acc2 = {0.f,0.f,0.f,0.f}, acc3 = {0.f,0.f,0.f,0.f};
            // ---- K-half 0 with wfA
            __builtin_amdgcn_s_setprio(1);
#pragma unroll
            for (int s = 0; s < 4; ++s) {
                acc0 = __builtin_amdgcn_mfma_f32_16x16x32_bf16(wfA[s], afE[0][s], acc0, 0, 0, 0);
                acc1 = __builtin_amdgcn_mfma_f32_16x16x32_bf16(wfA[s], afE[1][s], acc1, 0, 0, 0);
            }
#pragma unroll
            for (int s = 0; s < 4; ++s)
                sb[s] = *(const bf16x8*)&sm.stash[c * ASH + 32 * s + 8 * g];
#pragma unroll
            for (int s = 0; s < 4; ++s)
                acc2 = __builtin_amdgcn_mfma_f32_16x16x32_bf16(wfA[s], sb[s], acc2, 0, 0, 0);
#pragma unroll
            for (int s = 0; s < 4; ++s)
                sb[s] = *(const bf16x8*)&sm.stash[(NI + c) * ASH + 32 * s + 8 * g];
#pragma unroll
            for (int s = 0; s < 4; ++s)
                acc3 = __builtin_amdgcn_mfma_f32_16x16x32_bf16(wfA[s], sb[s], acc3, 0, 0, 0);
            __builtin_amdgcn_s_setprio(0);
            // ---- prefetch next chunk's K-half 0 (unconditional; hides under wfB MFMAs)
#pragma unroll
            for (int s = 0; s < 4; ++s)
                wfA[s] = *(const bf16x8*)(cb + 8192 + s * 512);
            // ---- K-half 1 with wfB
            __builtin_amdgcn_s_setprio(1);
#pragma unroll
            for (int s = 0; s < 4; ++s) {
                acc0 = __builtin_amdgcn_mfma_f32_16x16x32_bf16(wfB[s], afE[0][4 + s], acc0, 0, 0, 0);
                acc1 = __builtin_amdgcn_mfma_f32_16x16x32_bf16(wfB[s], afE[1][4 + s], acc1, 0, 0, 0);
            }
#pragma unroll
            for (int s = 0; s < 4; ++s)
                sb[s] = *(const bf16x8*)&sm.stash[c * ASH + 32 * (4 + s) + 8 * g];
#pragma unroll
            for (int s = 0; s < 4; ++s)
                acc2 = __builtin_amdgcn_mfma_f32_16x16x32_bf16(wfB[s], sb[s], acc2, 0, 0, 0);
#pragma unroll
            for (int s = 0; s < 4; ++s)
                sb[s] = *(const bf16x8*)&sm.stash[(NI + c) * ASH + 32 * (4 + s) + 8 * g];
#pragma unroll
            for (int s = 0; s < 4; ++s)
                acc3 = __builtin_amdgcn_mfma_f32_16x16x32_bf16(wfB[s], sb[s], acc3, 0, 0, 0);
            __builtin_amdgcn_s_setprio(0);

            // ---- epilogues (4 els): h[el][c][j] = tanh(acc + gv) + h_old
#pragma unroll
            for (int el = 0; el < 4; ++el) {
                f32x4 acc = (el == 0) ? acc0 : (el == 1) ? acc1 : (el == 2) ? acc2 : acc3;
                const uint2 gd = *(const uint2*)&sm.gmgv[el * HD + ch * 16 + j4];
                unsigned short* hrow = &sm.u.h[(el * NI + c) * ASH + ch * 16 + j4];
                uint2 hd2 = *(const uint2*)hrow;
                float f0 = tanh5(acc[0] + bflo(gd.x)) + bflo(hd2.x);
                float f1 = tanh5(acc[1] + bfhi(gd.x)) + bfhi(hd2.x);
                float f2 = tanh5(acc[2] + bflo(gd.y)) + bflo(hd2.y);
                float f3 = tanh5(acc[3] + bfhi(gd.y)) + bfhi(hd2.y);
                uint2 wo; wo.x = cvt_pk_bf16(f0, f1); wo.y = cvt_pk_bf16(f2, f3);
                *(uint2*)hrow = wo;
            }
        }
        LGKM_BAR();   // (A) all strips' epilogue writes + stash reads done
    }

    // ---- slater head: wave e = w owns element e; Wsl frags from global (chunk 48)
    {
        const int e = w;
        bf16x8 sb8[8];
#pragma unroll
        for (int s = 0; s < 8; ++s)
            sb8[s] = *(const bf16x8*)&sm.u.h[(e * NI + c) * ASH + 32 * s + 8 * g];
        const unsigned short* cb = wlane + (size_t)48 * 8192;
        f32x4 a0 = {0.f,0.f,0.f,0.f}, a1 = {0.f,0.f,0.f,0.f};
        __builtin_amdgcn_s_setprio(1);
#pragma unroll
        for (int s = 0; s < 4; ++s) {
            bf16x8 b0 = *(const bf16x8*)(cb + (2 * s) * 512);
            bf16x8 b1 = *(const bf16x8*)(cb + (2 * s + 1) * 512);
            a0 = __builtin_amdgcn_mfma_f32_16x16x32_bf16(b0, sb8[2 * s],     a0, 0, 0, 0);
            a1 = __builtin_amdgcn_mfma_f32_16x16x32_bf16(b1, sb8[2 * s + 1], a1, 0, 0, 0);
        }
        __builtin_amdgcn_s_setprio(0);
        f32x4 sv = a0 + a1;   // lane (g,c): sl[row r=c][m=4g+q]
        const float4 bsv = *(const float4*)&bsl[j4];
        float* slp = &sm.u.slf[e][0];   // overlays own element's h (now dead)
        float4 o;
        o.x = sv[0] + bsv.x; o.y = sv[1] + bsv.y;
        o.z = sv[2] + bsv.z; o.w = sv[3] + bsv.w;
        *(float4*)&slp[c * SLS + j4] = o;
    }
    LGKM_WAIT();   // in-wave: slf visible

    // ---- per-wave slogdet: swap-free LU w/ partial pivoting (R11-R20 verified)
    {
        const int e = w;
        const float* slp = &sm.u.slf[e][0];
        const int i = c;
        float M[16];
#pragma unroll
        for (int jj = 0; jj < 4; ++jj) {
            float4 vv = *(const float4*)&slp[i * SLS + 4 * jj];
            M[4 * jj] = vv.x; M[4 * jj + 1] = vv.y; M[4 * jj + 2] = vv.z; M[4 * jj + 3] = vv.w;
        }

        int elim = 0;
        unsigned chosen = 0;
        int invcnt = 0;
        float dsign = 1.f, logabs = 0.f;
#pragma unroll
        for (int k = 0; k < 16; ++k) {
            float myv = elim ? -1.f : __builtin_fabsf(M[k]);
            float maxv = myv;
#pragma unroll
            for (int off = 8; off > 0; off >>= 1)
                maxv = fmaxf(maxv, __shfl_xor(maxv, off));
            unsigned long long bal = __ballot(myv == maxv);
            const int p = (__ffsll((long long)bal) - 1) & 15;

            invcnt += __popc(chosen >> (p + 1));
            chosen |= 1u << p;
            if (i == p) elim = 1;

            float piv = bcast(M[k], p);
            float ap = fmaxf(__builtin_fabsf(piv), 1e-35f);
            logabs += __logf(ap);
            if (piv < 0.f) dsign = -dsign;
            float spiv = __builtin_copysignf(ap, piv);
            float mi = __fdividef(M[k], spiv);
#pragma unroll
            for (int j = k + 1; j < 16; ++j) {
                float pr = bcast(M[j], p);
                if (!elim) M[j] = __builtin_fmaf(-mi, pr, M[j]);
            }
        }
        if (invcnt & 1) dsign = -dsign;

        float xv = (l < NI) ? x0g[(bbase + w) * NI + l] : 0.f;
        float sq = xv * xv;
#pragma unroll
        for (int off = 8; off > 0; off >>= 1) sq += __shfl_xor(sq, off);

        if (l == 0) {
            out[bbase + w] = dsign;
            out[BTOT + bbase + w] = logabs - HALF_LOGFACT - width[0] * sq;
        }
    }
}

extern "C" void kernel_launch(void* const* d_in, const int* in_sizes, int n_in,
                              void* d_out, int out_size, void* d_ws, size_t ws_size,
                              hipStream_t stream) {
    const float* x0   = (const float*)d_in[0];
    const float* Win  = (const float*)d_in[1];
    const float* bin  = (const float*)d_in[2];
    const float* Wmid = (const float*)d_in[3];
    const float* bmid = (const float*)d_in[4];
    const float* Wsl  = (const float*)d_in[5];
    const float* bsl  = (const float*)d_in[6];
    const float* wid  = (const float*)d_in[7];
    float* out = (float*)d_out;

    unsigned short* wtc = (unsigned short*)d_ws;   // 49 * 16384 B = 802816 B

    hipLaunchKernelGGL(prep_w, dim3(49), dim3(256), 0, stream, Wmid, Wsl, wtc);
    hipLaunchKernelGGL(eqslater_mfma, dim3(BTOT / BB), dim3(256), 0, stream,
                       x0, Win, bin, bmid, bsl, wid, wtc, out);
}